// Round 8
// baseline (309.291 us; speedup 1.0000x reference)
//
#include <hip/hip_runtime.h>

typedef unsigned int uint;
typedef unsigned short ushort;

#define NN 50000
#define NE 600000
#define DIM 128
#define KD 384   // K*DIM
#define PADK 40  // LDS row stride (ushorts) for MFMA tiles

typedef __attribute__((ext_vector_type(8))) short short8;
typedef __attribute__((ext_vector_type(4))) float float4v;

static __device__ __forceinline__ ushort f2b(float f) {   // fp32 -> bf16 RNE
    uint u = __float_as_uint(f);
    return (ushort)((u + 0x7FFFu + ((u >> 16) & 1u)) >> 16);
}
static __device__ __forceinline__ float blo(uint u) { return __uint_as_float(u << 16); }
static __device__ __forceinline__ float bhi(uint u) { return __uint_as_float(u & 0xFFFF0000u); }
static __device__ __forceinline__ float asf(uint u) { return __uint_as_float(u); }

// blocks 0..48: zero cnt (50176 ints)
// blocks 49..624: transpose weights cheb_w [3][384][128] fp32 -> Wt [3][128][384] bf16
// blocks 625..630: uv vectors u_t = lin_w @ W_t, v_t = lin_b @ W_t
__global__ void k_init(int* __restrict__ cnt, const float* __restrict__ cw,
                       ushort* __restrict__ wt, const float* __restrict__ lw,
                       const float* __restrict__ lb, float* __restrict__ uvout) {
    if (blockIdx.x < 49) {
        int i = blockIdx.x * 256 + threadIdx.x;
        if (i < 12544) ((int4*)cnt)[i] = make_int4(0, 0, 0, 0);
    } else if (blockIdx.x < 625) {
        int i = (blockIdx.x - 49) * 256 + threadIdx.x;
        if (i < 3 * KD * DIM) {
            int l = i / (KD * DIM), rem = i - l * (KD * DIM);
            int k = rem >> 7, n = rem & 127;
            wt[(size_t)l * KD * DIM + (size_t)n * KD + k] = f2b(cw[i]);
        }
    } else {
        int vec = blockIdx.x - 625;        // 0..5: u0,v0,u1,v1,u2,v2
        int t = vec >> 1;
        const float* coef = (vec & 1) ? lb : lw;
        int c = threadIdx.x;
        if (c < 128) {
            float s = 0.f;
#pragma unroll 8
            for (int k = 0; k < 128; ++k)
                s = fmaf(coef[k], cw[(size_t)(t * 128 + k) * 128 + c], s);
            uvout[vec * 128 + c] = s;
        }
    }
}

// Histogram + per-edge rank (atomic return value). The only atomic pass.
__global__ void k_hist(const int* __restrict__ dst, int* __restrict__ cnt,
                       int* __restrict__ rank) {
    int e = blockIdx.x * 256 + threadIdx.x;
    if (e < NE) rank[e] = atomicAdd(&cnt[dst[e]], 1);
}

// Block scan of cnt -> incl, block totals -> bsums.
// Also writes nrec[n].{x,y} = {bits(dinv), bits(w)}.
__global__ __launch_bounds__(256) void k_scan1(const int* __restrict__ cnt,
                                               int* __restrict__ incl,
                                               int* __restrict__ bsums,
                                               const float* __restrict__ w,
                                               uint4* __restrict__ nrec) {
    __shared__ int sh[256];
    int i = blockIdx.x * 256 + threadIdx.x;
    int v = (i < NN) ? cnt[i] : 0;
    if (i < NN) {
        uint2 r;
        r.x = __float_as_uint(rsqrtf((float)(v + 1)));   // +1 self-loop
        r.y = __float_as_uint(w[i]);
        ((uint2*)nrec)[2 * i] = r;
    }
    sh[threadIdx.x] = v;
    __syncthreads();
    for (int d = 1; d < 256; d <<= 1) {
        int t = (threadIdx.x >= d) ? sh[threadIdx.x - d] : 0;
        __syncthreads();
        sh[threadIdx.x] += t;
        __syncthreads();
    }
    incl[i] = sh[threadIdx.x];
    if (threadIdx.x == 255) bsums[blockIdx.x] = sh[255];
}

// Each block prefix-sums the 196 block totals itself, then emits offs.
__global__ __launch_bounds__(256) void k_scan3(const int* __restrict__ cnt,
                                               const int* __restrict__ incl,
                                               const int* __restrict__ bsums,
                                               int* __restrict__ offs) {
    __shared__ int sh[256];
    __shared__ int boff;
    int tid = threadIdx.x;
    int v = (tid < 196) ? bsums[tid] : 0;
    sh[tid] = v;
    __syncthreads();
    for (int d = 1; d < 256; d <<= 1) {
        int t = (tid >= d) ? sh[tid - d] : 0;
        __syncthreads();
        sh[tid] += t;
        __syncthreads();
    }
    if (tid == blockIdx.x) boff = sh[tid] - v;   // exclusive prefix for this block
    __syncthreads();
    int i = blockIdx.x * 256 + tid;
    if (i >= NN) return;
    offs[i] = incl[i] - cnt[i] + boff;
    if (i == NN - 1) offs[NN] = NE;
}

// Minimal scatter: csrS[offs[dst]+rank] = src. 4B random read + 4B scatter.
__global__ void k_fill4(const int* __restrict__ src, const int* __restrict__ dst,
                        const int* __restrict__ rank, const int* __restrict__ offs,
                        uint* __restrict__ csrS) {
    int e = blockIdx.x * 256 + threadIdx.x;
    if (e < NE) {
        int p = offs[dst[e]] + rank[e];
        csrS[p] = (uint)src[e];
    }
}

// CSR finalize + scalar SpMV #1 fused. Node-parallel (16 lanes/node):
// reads csrS segment coalesced, nrec[s] random 16B, writes csrE2 coalesced,
// and reduces SS[n] = { Sw[n], S1[n] } in the same lane-stride order as the
// old k_spmv1 (bit-identical).
__global__ __launch_bounds__(256) void k_csrfin(
        const int* __restrict__ offs, const uint* __restrict__ csrS,
        const uint4* __restrict__ nrec, uint4* __restrict__ csrE2,
        float2* __restrict__ SS) {
    int n = blockIdx.x * 16 + (threadIdx.x >> 4);
    int l = threadIdx.x & 15;
    int j0 = offs[n], j1 = offs[n + 1];
    uint4 nr_n = nrec[n];
    float dn = asf(nr_n.x);
    float sA = 0.f, sB = 0.f;
    for (int j = j0 + l; j < j1; j += 16) {
        uint s = csrS[j];
        uint4 nr = nrec[s];
        float ds = asf(nr.x);
        float wv = ds * dn;              // dinv[s]*dinv[n]
        float hw = ds * asf(nr.y);       // dinv[s]*w[s]
        uint4 rec;
        rec.x = s;
        rec.y = __float_as_uint(wv);
        rec.z = __float_as_uint(hw);
        rec.w = 0;
        csrE2[j] = rec;
        sA += hw;
        sB += wv;
    }
#pragma unroll
    for (int off = 8; off > 0; off >>= 1) {
        sA += __shfl_down(sA, off, 16);
        sB += __shfl_down(sB, off, 16);
    }
    if (l == 0) {
        float id = dn * dn;
        float2 o;
        o.x = dn * sA + id * asf(nr_n.y);
        o.y = sB + id;
        SS[n] = o;
    }
}

// Fused SpMV #2 + layer-1 output (row-major bf16 Pb).
__global__ __launch_bounds__(256) void k_spmv2l1(
        const int* __restrict__ offs, const uint4* __restrict__ csrE2,
        const float2* __restrict__ SS, const uint4* __restrict__ nrec,
        const float* __restrict__ uv, const float* __restrict__ bias,
        ushort* __restrict__ Pb) {
    __shared__ float suv[768];
    __shared__ float sbias[128];
    int tid = threadIdx.x;
    for (int i = tid; i < 768; i += 256) suv[i] = uv[i];
    if (tid < 128) sbias[tid] = bias[tid];
    __syncthreads();

    int n = blockIdx.x * 16 + (tid >> 4);
    int l = tid & 15;
    int j0 = offs[n], j1 = offs[n + 1];
    float sC = 0.f, sD = 0.f;
    for (int j = j0 + l; j < j1; j += 16) {
        uint4 q = csrE2[j];
        float wv = asf(q.y);
        float2 s = SS[q.x];
        sC = fmaf(wv, s.x, sC);
        sD = fmaf(wv, s.y, sD);
    }
#pragma unroll
    for (int off = 8; off > 0; off >>= 1) {
        sC += __shfl_down(sC, off, 16);
        sD += __shfl_down(sD, off, 16);
    }
    sC = __shfl(sC, 0, 16);
    sD = __shfl(sD, 0, 16);

    uint4 nr = nrec[n];
    float dn = asf(nr.x), id = dn * dn;
    float2 s = SS[n];
    float ssw = sC + id * s.x;
    float ss1 = sD + id * s.y;
    float a0 = asf(nr.y);
    float a1 = -s.x, b1 = -s.y;
    float a2 = 2.f * ssw - a0, b2 = 2.f * ss1 - 1.f;

    const float2* uv2 = (const float2*)suv;
    uint r[4];
#pragma unroll
    for (int q = 0; q < 4; ++q) {
        int p = 4 * l + q;   // float2 index: dims 8l+2q, 8l+2q+1
        float2 u0 = uv2[p],       v0 = uv2[64 + p];
        float2 u1 = uv2[128 + p], v1 = uv2[192 + p];
        float2 u2 = uv2[256 + p], v2 = uv2[320 + p];
        float2 bb = ((const float2*)sbias)[p];
        float o0 = bb.x + a0 * u0.x + v0.x + a1 * u1.x + b1 * v1.x + a2 * u2.x + b2 * v2.x;
        float o1 = bb.y + a0 * u0.y + v0.y + a1 * u1.y + b1 * v1.y + a2 * u2.y + b2 * v2.y;
        r[q] = (uint)f2b(fmaxf(o0, 0.f)) | ((uint)f2b(fmaxf(o1, 0.f)) << 16);
    }
    uint4 w4; w4.x = r[0]; w4.y = r[1]; w4.z = r[2]; w4.w = r[3];
    ((uint4*)(Pb + (size_t)n * DIM))[l] = w4;   // 16 lanes x 16 B = 256 B row
}

// One node per wave64: edge stream wave-uniform (s_load dwordx4), row load
// one coalesced 4B/lane (= full 256B bf16 row), zero shuffles, unroll 8.
// Qb[n] = bf16( -( sum w_e*Xb[src] + Xb[n]/deg ) )
__global__ __launch_bounds__(256) void k_gather1(
        const ushort* __restrict__ Xb, const int* __restrict__ offs,
        const uint4* __restrict__ csrE2, const uint4* __restrict__ nrec,
        ushort* __restrict__ Qb) {
    int n = __builtin_amdgcn_readfirstlane(blockIdx.x * 4 + (threadIdx.x >> 6));
    int lane = threadIdx.x & 63;
    int j0 = offs[n], j1 = offs[n + 1];
    const uint* Xu = (const uint*)Xb;   // row = 64 uints
    uint un = Xu[(size_t)n * 64 + lane];
    float dn = asf(nrec[n].x);
    float a0 = 0.f, a1 = 0.f;
#pragma unroll 8
    for (int j = j0; j < j1; ++j) {
        uint4 e = csrE2[j];              // wave-uniform -> s_load_dwordx4
        float wv = asf(e.y);
        uint u = Xu[(size_t)e.x * 64 + lane];
        a0 = fmaf(wv, blo(u), a0);
        a1 = fmaf(wv, bhi(u), a1);
    }
    float id = dn * dn;
    uint ow = (uint)f2b(-(a0 + blo(un) * id))
            | ((uint)f2b(-(a1 + bhi(un) * id)) << 16);
    ((uint*)Qb)[(size_t)n * 64 + lane] = ow;
}

// Rb[n] = bf16( -2*( sum w_e*X1b[src] + X1b[n]/deg ) - X0b[n] )
__global__ __launch_bounds__(256) void k_gather2(
        const ushort* __restrict__ X1b, const ushort* __restrict__ X0b,
        const int* __restrict__ offs, const uint4* __restrict__ csrE2,
        const uint4* __restrict__ nrec, ushort* __restrict__ Rb) {
    int n = __builtin_amdgcn_readfirstlane(blockIdx.x * 4 + (threadIdx.x >> 6));
    int lane = threadIdx.x & 63;
    int j0 = offs[n], j1 = offs[n + 1];
    const uint* Xu = (const uint*)X1b;
    uint u1n = Xu[(size_t)n * 64 + lane];
    uint u0n = ((const uint*)X0b)[(size_t)n * 64 + lane];
    float dn = asf(nrec[n].x);
    float a0 = 0.f, a1 = 0.f;
#pragma unroll 8
    for (int j = j0; j < j1; ++j) {
        uint4 e = csrE2[j];              // wave-uniform -> s_load_dwordx4
        float wv = asf(e.y);
        uint u = Xu[(size_t)e.x * 64 + lane];
        a0 = fmaf(wv, blo(u), a0);
        a1 = fmaf(wv, bhi(u), a1);
    }
    float id = dn * dn;
    uint ow = (uint)f2b(-2.f * (a0 + blo(u1n) * id) - blo(u0n))
            | ((uint)f2b(-2.f * (a1 + bhi(u1n) * id) - bhi(u0n)) << 16);
    ((uint*)Rb)[(size_t)n * 64 + lane] = ow;
}

// MFMA GEMM: outb = bf16(relu([X0|X1|X2] @ W + bias)). 128x128 per block,
// 4 waves each 64x64 quadrant as 4x4 16x16x32 bf16 MFMA tiles.
// Aliasing (outb == X0b) safe: block reads only its own 128 rows, writes last.
__global__ __launch_bounds__(256) void k_gemm(
        const ushort* __restrict__ X0b, const ushort* __restrict__ X1b,
        const ushort* __restrict__ X2b, const ushort* __restrict__ Wt,
        const float* __restrict__ bias, ushort* __restrict__ outb) {
    __shared__ ushort As[128 * PADK];
    __shared__ ushort Bs[128 * PADK];
    int tid = threadIdx.x;
    int nbase = blockIdx.x * 128;
    int wave = tid >> 6, lane = tid & 63;
    int wr = wave >> 1, wc = wave & 1;
    int l15 = lane & 15, quad = lane >> 4;

    float4v acc[4][4];
#pragma unroll
    for (int i = 0; i < 4; ++i)
#pragma unroll
        for (int j = 0; j < 4; ++j) acc[i][j] = (float4v)0.f;

    int srow = tid >> 1, shalf = tid & 1;
    int gm = nbase + srow; if (gm >= NN) gm = NN - 1;

    for (int c = 0; c < 12; ++c) {
        int part = c >> 2;
        int k0 = (c & 3) * 32;
        const ushort* Xp = (part == 0) ? X0b : ((part == 1) ? X1b : X2b);
        const uint4* ga = (const uint4*)(Xp + (size_t)gm * DIM + k0 + shalf * 16);
        uint4 a0 = ga[0], a1 = ga[1];
        const uint4* gb = (const uint4*)(Wt + (size_t)srow * KD + c * 32 + shalf * 16);
        uint4 b0 = gb[0], b1 = gb[1];
        __syncthreads();
        uint4* pa = (uint4*)(As + srow * PADK + shalf * 16);
        pa[0] = a0; pa[1] = a1;
        uint4* pb = (uint4*)(Bs + srow * PADK + shalf * 16);
        pb[0] = b0; pb[1] = b1;
        __syncthreads();
        short8 af[4], bf[4];
#pragma unroll
        for (int i = 0; i < 4; ++i) {
            af[i] = *(const short8*)(As + (wr * 64 + i * 16 + l15) * PADK + quad * 8);
            bf[i] = *(const short8*)(Bs + (wc * 64 + i * 16 + l15) * PADK + quad * 8);
        }
#pragma unroll
        for (int i = 0; i < 4; ++i)
#pragma unroll
            for (int j = 0; j < 4; ++j)
                acc[i][j] = __builtin_amdgcn_mfma_f32_16x16x32_bf16(
                    af[i], bf[j], acc[i][j], 0, 0, 0);
    }

    float bv[4];
#pragma unroll
    for (int j = 0; j < 4; ++j) bv[j] = bias[wc * 64 + j * 16 + l15];
#pragma unroll
    for (int i = 0; i < 4; ++i) {
#pragma unroll
        for (int r = 0; r < 4; ++r) {
            int node = nbase + wr * 64 + i * 16 + quad * 4 + r;
            if (node < NN) {
#pragma unroll
                for (int j = 0; j < 4; ++j) {
                    int col = wc * 64 + j * 16 + l15;
                    outb[(size_t)node * DIM + col] =
                        f2b(fmaxf(acc[i][j][r] + bv[j], 0.f));
                }
            }
        }
    }
}

// Last-layer GEMM with fused prediction head.
__global__ __launch_bounds__(256) void k_gemm_pred(
        const ushort* __restrict__ X0b, const ushort* __restrict__ X1b,
        const ushort* __restrict__ X2b, const ushort* __restrict__ Wt,
        const float* __restrict__ bias, const float* __restrict__ pw,
        const float* __restrict__ pb, float* __restrict__ logits) {
    __shared__ ushort As[128 * PADK];
    __shared__ ushort Bs[128 * PADK];
    __shared__ float lsum[128];
    int tid = threadIdx.x;
    int nbase = blockIdx.x * 128;
    int wave = tid >> 6, lane = tid & 63;
    int wr = wave >> 1, wc = wave & 1;
    int l15 = lane & 15, quad = lane >> 4;

    float4v acc[4][4];
#pragma unroll
    for (int i = 0; i < 4; ++i)
#pragma unroll
        for (int j = 0; j < 4; ++j) acc[i][j] = (float4v)0.f;

    int srow = tid >> 1, shalf = tid & 1;
    int gm = nbase + srow; if (gm >= NN) gm = NN - 1;

    for (int c = 0; c < 12; ++c) {
        int part = c >> 2;
        int k0 = (c & 3) * 32;
        const ushort* Xp = (part == 0) ? X0b : ((part == 1) ? X1b : X2b);
        const uint4* ga = (const uint4*)(Xp + (size_t)gm * DIM + k0 + shalf * 16);
        uint4 a0 = ga[0], a1 = ga[1];
        const uint4* gb = (const uint4*)(Wt + (size_t)srow * KD + c * 32 + shalf * 16);
        uint4 b0 = gb[0], b1 = gb[1];
        __syncthreads();
        uint4* pa = (uint4*)(As + srow * PADK + shalf * 16);
        pa[0] = a0; pa[1] = a1;
        uint4* pb2 = (uint4*)(Bs + srow * PADK + shalf * 16);
        pb2[0] = b0; pb2[1] = b1;
        __syncthreads();
        short8 af[4], bf[4];
#pragma unroll
        for (int i = 0; i < 4; ++i) {
            af[i] = *(const short8*)(As + (wr * 64 + i * 16 + l15) * PADK + quad * 8);
            bf[i] = *(const short8*)(Bs + (wc * 64 + i * 16 + l15) * PADK + quad * 8);
        }
#pragma unroll
        for (int i = 0; i < 4; ++i)
#pragma unroll
            for (int j = 0; j < 4; ++j)
                acc[i][j] = __builtin_amdgcn_mfma_f32_16x16x32_bf16(
                    af[i], bf[j], acc[i][j], 0, 0, 0);
    }

    __syncthreads();
    if (tid < 128) lsum[tid] = 0.f;
    __syncthreads();
    float bv[4], pwv[4];
#pragma unroll
    for (int j = 0; j < 4; ++j) {
        int col = wc * 64 + j * 16 + l15;
        bv[j] = bias[col];
        pwv[j] = pw[col];
    }
#pragma unroll
    for (int i = 0; i < 4; ++i) {
#pragma unroll
        for (int r = 0; r < 4; ++r) {
            float local = 0.f;
#pragma unroll
            for (int j = 0; j < 4; ++j)
                local = fmaf(fmaxf(acc[i][j][r] + bv[j], 0.f), pwv[j], local);
            local += __shfl_xor(local, 1, 64);
            local += __shfl_xor(local, 2, 64);
            local += __shfl_xor(local, 4, 64);
            local += __shfl_xor(local, 8, 64);
            if (l15 == 0)
                atomicAdd(&lsum[wr * 64 + i * 16 + quad * 4 + r], local);
        }
    }
    __syncthreads();
    if (tid < 128) {
        int node = nbase + tid;
        if (node < NN) logits[node] = lsum[tid] + pb[0];
    }
}

extern "C" void kernel_launch(void* const* d_in, const int* in_sizes, int n_in,
                              void* d_out, int out_size, void* d_ws, size_t ws_size,
                              hipStream_t stream) {
    int i_weights = 0, i_src = 1, i_dst = 2, i_lw = 3, i_lb = 4,
        i_cw = 5, i_cb = 6, i_pw = 7, i_pb = 8;
    {
        int seen600k = 0, seen128 = 0;
        for (int i = 0; i < n_in; ++i) {
            int s = in_sizes[i];
            if (s == 50000) i_weights = i;
            else if (s == 600000) { if (seen600k == 0) i_src = i; else i_dst = i; ++seen600k; }
            else if (s == 128) { if (seen128 == 0) i_lw = i; else if (seen128 == 1) i_lb = i; else i_pw = i; ++seen128; }
            else if (s == 147456) i_cw = i;
            else if (s == 384) i_cb = i;
            else if (s == 1) i_pb = i;
        }
    }
    const float* weights = (const float*)d_in[i_weights];
    const int*   src     = (const int*)d_in[i_src];
    const int*   dst     = (const int*)d_in[i_dst];
    const float* lin_w   = (const float*)d_in[i_lw];
    const float* lin_b   = (const float*)d_in[i_lb];
    const float* cheb_w  = (const float*)d_in[i_cw];
    const float* cheb_b  = (const float*)d_in[i_cb];
    const float* pred_w  = (const float*)d_in[i_pw];
    const float* pred_b  = (const float*)d_in[i_pb];
    float* out = (float*)d_out;

    // Workspace (~32 MB), 16B-aligned blocks first:
    uint4*  csrE2   = (uint4*)d_ws;                  // 600000 x 16B {src,w,hw,0}
    uint4*  nrec    = csrE2 + NE;                    // 50048 x 16B {dinv,w,-,-}
    float2* SS      = (float2*)(nrec + 50048);       // 50048 float2 {Sw, S1}
    float*  uv      = (float*)(SS + 50048);          // 768 floats
    int*    offs    = (int*)(uv + 768);              // 50056 ints
    int*    cnt     = offs + 50056;                  // 50176 ints
    int*    incl    = cnt + 50176;                   // 50176 ints
    int*    bsums   = incl + 50176;                  // 256 ints
    int*    rank    = bsums + 256;                   // 600000 ints
    uint*   csrS    = (uint*)(rank + NE);            // 600000 uints
    ushort* Pb      = (ushort*)(csrS + NE);          // 6.4M bf16 (state)
    ushort* Qb      = Pb + (size_t)NN * DIM;         // 6.4M bf16 (X1)
    ushort* Rb      = Qb + (size_t)NN * DIM;         // 6.4M bf16 (X2)
    ushort* Wtb     = Rb + (size_t)NN * DIM;         // 442368 bf16

    // --- CSR build + weight transpose + uv (once per launch) ---
    k_init<<<631, 256, 0, stream>>>(cnt, cheb_w, Wtb, lin_w, lin_b, uv);
    k_hist<<<2344, 256, 0, stream>>>(dst, cnt, rank);
    k_scan1<<<196, 256, 0, stream>>>(cnt, incl, bsums, weights, nrec);
    k_scan3<<<196, 256, 0, stream>>>(cnt, incl, bsums, offs);
    k_fill4<<<2344, 256, 0, stream>>>(src, dst, rank, offs, csrS);
    k_csrfin<<<3125, 256, 0, stream>>>(offs, csrS, nrec, csrE2, SS);

    // --- layer 1: fused SpMV #2 + layer-1 output ---
    k_spmv2l1<<<3125, 256, 0, stream>>>(offs, csrE2, SS, nrec, uv, cheb_b, Pb);

    // --- layer 2 ---
    k_gather1<<<12500, 256, 0, stream>>>(Pb, offs, csrE2, nrec, Qb);
    k_gather2<<<12500, 256, 0, stream>>>(Qb, Pb, offs, csrE2, nrec, Rb);
    k_gemm<<<391, 256, 0, stream>>>(Pb, Qb, Rb, Wtb + (size_t)KD * DIM,
                                    cheb_b + DIM, Pb);
    // --- layer 3 (fused prediction head) ---
    k_gather1<<<12500, 256, 0, stream>>>(Pb, offs, csrE2, nrec, Qb);
    k_gather2<<<12500, 256, 0, stream>>>(Qb, Pb, offs, csrE2, nrec, Rb);
    k_gemm_pred<<<391, 256, 0, stream>>>(Pb, Qb, Rb, Wtb + (size_t)2 * KD * DIM,
                                         cheb_b + 2 * DIM, pred_w, pred_b, out);
}

// Round 9
// 296.414 us; speedup vs baseline: 1.0434x; 1.0434x over previous
//
#include <hip/hip_runtime.h>

typedef unsigned int uint;
typedef unsigned short ushort;

#define NN 50000
#define NE 600000
#define DIM 128
#define KD 384   // K*DIM
#define PADK 40  // LDS row stride (ushorts) for MFMA tiles

typedef __attribute__((ext_vector_type(8))) short short8;
typedef __attribute__((ext_vector_type(4))) float float4v;

static __device__ __forceinline__ ushort f2b(float f) {   // fp32 -> bf16 RNE
    uint u = __float_as_uint(f);
    return (ushort)((u + 0x7FFFu + ((u >> 16) & 1u)) >> 16);
}
static __device__ __forceinline__ float blo(uint u) { return __uint_as_float(u << 16); }
static __device__ __forceinline__ float bhi(uint u) { return __uint_as_float(u & 0xFFFF0000u); }
static __device__ __forceinline__ float asf(uint u) { return __uint_as_float(u); }

// blocks 0..48: zero cnt (50176 ints)
// blocks 49..624: transpose weights cheb_w [3][384][128] fp32 -> Wt [3][128][384] bf16
// blocks 625..630: uv vectors u_t = lin_w @ W_t, v_t = lin_b @ W_t
__global__ void k_init(int* __restrict__ cnt, const float* __restrict__ cw,
                       ushort* __restrict__ wt, const float* __restrict__ lw,
                       const float* __restrict__ lb, float* __restrict__ uvout) {
    if (blockIdx.x < 49) {
        int i = blockIdx.x * 256 + threadIdx.x;
        if (i < 12544) ((int4*)cnt)[i] = make_int4(0, 0, 0, 0);
    } else if (blockIdx.x < 625) {
        int i = (blockIdx.x - 49) * 256 + threadIdx.x;
        if (i < 3 * KD * DIM) {
            int l = i / (KD * DIM), rem = i - l * (KD * DIM);
            int k = rem >> 7, n = rem & 127;
            wt[(size_t)l * KD * DIM + (size_t)n * KD + k] = f2b(cw[i]);
        }
    } else {
        int vec = blockIdx.x - 625;        // 0..5: u0,v0,u1,v1,u2,v2
        int t = vec >> 1;
        const float* coef = (vec & 1) ? lb : lw;
        int c = threadIdx.x;
        if (c < 128) {
            float s = 0.f;
#pragma unroll 8
            for (int k = 0; k < 128; ++k)
                s = fmaf(coef[k], cw[(size_t)(t * 128 + k) * 128 + c], s);
            uvout[vec * 128 + c] = s;
        }
    }
}

// Histogram + per-edge rank (atomic return value). The only atomic pass.
__global__ void k_hist(const int* __restrict__ dst, int* __restrict__ cnt,
                       int* __restrict__ rank) {
    int e = blockIdx.x * 256 + threadIdx.x;
    if (e < NE) rank[e] = atomicAdd(&cnt[dst[e]], 1);
}

// Block scan of cnt -> incl, block totals -> bsums.
// Also writes nrec[n] = {bits(dinv), bits(w)}  (8B).
__global__ __launch_bounds__(256) void k_scan1(const int* __restrict__ cnt,
                                               int* __restrict__ incl,
                                               int* __restrict__ bsums,
                                               const float* __restrict__ w,
                                               uint2* __restrict__ nrec) {
    __shared__ int sh[256];
    int i = blockIdx.x * 256 + threadIdx.x;
    int v = (i < NN) ? cnt[i] : 0;
    if (i < NN) {
        uint2 r;
        r.x = __float_as_uint(rsqrtf((float)(v + 1)));   // +1 self-loop
        r.y = __float_as_uint(w[i]);
        nrec[i] = r;
    }
    sh[threadIdx.x] = v;
    __syncthreads();
    for (int d = 1; d < 256; d <<= 1) {
        int t = (threadIdx.x >= d) ? sh[threadIdx.x - d] : 0;
        __syncthreads();
        sh[threadIdx.x] += t;
        __syncthreads();
    }
    incl[i] = sh[threadIdx.x];
    if (threadIdx.x == 255) bsums[blockIdx.x] = sh[255];
}

// Each block prefix-sums the 196 block totals itself, then emits offs.
__global__ __launch_bounds__(256) void k_scan3(const int* __restrict__ cnt,
                                               const int* __restrict__ incl,
                                               const int* __restrict__ bsums,
                                               int* __restrict__ offs) {
    __shared__ int sh[256];
    __shared__ int boff;
    int tid = threadIdx.x;
    int v = (tid < 196) ? bsums[tid] : 0;
    sh[tid] = v;
    __syncthreads();
    for (int d = 1; d < 256; d <<= 1) {
        int t = (tid >= d) ? sh[tid - d] : 0;
        __syncthreads();
        sh[tid] += t;
        __syncthreads();
    }
    if (tid == blockIdx.x) boff = sh[tid] - v;   // exclusive prefix for this block
    __syncthreads();
    int i = blockIdx.x * 256 + tid;
    if (i >= NN) return;
    offs[i] = incl[i] - cnt[i] + boff;
    if (i == NN - 1) offs[NN] = NE;
}

// Minimal scatter: csrS[offs[dst]+rank] = src. 4B random read + 4B scatter.
__global__ void k_fill4(const int* __restrict__ src, const int* __restrict__ dst,
                        const int* __restrict__ rank, const int* __restrict__ offs,
                        uint* __restrict__ csrS) {
    int e = blockIdx.x * 256 + threadIdx.x;
    if (e < NE) {
        int p = offs[dst[e]] + rank[e];
        csrS[p] = (uint)src[e];
    }
}

// CSR finalize + scalar SpMV #1 fused. Node-parallel (16 lanes/node):
// reads csrS segment coalesced, nrec[s] random 8B, writes csrE (8B records
// {src,w}) coalesced, and reduces SS[n] = { Sw[n], S1[n] } in the same
// lane-stride order as before (bit-identical). hw is consumed on the fly,
// never stored (it was dead in the old 16B record).
__global__ __launch_bounds__(256) void k_csrfin(
        const int* __restrict__ offs, const uint* __restrict__ csrS,
        const uint2* __restrict__ nrec, uint2* __restrict__ csrE,
        float2* __restrict__ SS) {
    int n = blockIdx.x * 16 + (threadIdx.x >> 4);
    int l = threadIdx.x & 15;
    int j0 = offs[n], j1 = offs[n + 1];
    uint2 nr_n = nrec[n];
    float dn = asf(nr_n.x);
    float sA = 0.f, sB = 0.f;
    for (int j = j0 + l; j < j1; j += 16) {
        uint s = csrS[j];
        uint2 nr = nrec[s];
        float ds = asf(nr.x);
        float wv = ds * dn;              // dinv[s]*dinv[n]
        float hw = ds * asf(nr.y);       // dinv[s]*w[s]
        uint2 rec;
        rec.x = s;
        rec.y = __float_as_uint(wv);
        csrE[j] = rec;
        sA += hw;
        sB += wv;
    }
#pragma unroll
    for (int off = 8; off > 0; off >>= 1) {
        sA += __shfl_down(sA, off, 16);
        sB += __shfl_down(sB, off, 16);
    }
    if (l == 0) {
        float id = dn * dn;
        float2 o;
        o.x = dn * sA + id * asf(nr_n.y);
        o.y = sB + id;
        SS[n] = o;
    }
}

// Fused SpMV #2 + layer-1 output (row-major bf16 Pb).
__global__ __launch_bounds__(256) void k_spmv2l1(
        const int* __restrict__ offs, const uint2* __restrict__ csrE,
        const float2* __restrict__ SS, const uint2* __restrict__ nrec,
        const float* __restrict__ uv, const float* __restrict__ bias,
        ushort* __restrict__ Pb) {
    __shared__ float suv[768];
    __shared__ float sbias[128];
    int tid = threadIdx.x;
    for (int i = tid; i < 768; i += 256) suv[i] = uv[i];
    if (tid < 128) sbias[tid] = bias[tid];
    __syncthreads();

    int n = blockIdx.x * 16 + (tid >> 4);
    int l = tid & 15;
    int j0 = offs[n], j1 = offs[n + 1];
    float sC = 0.f, sD = 0.f;
    for (int j = j0 + l; j < j1; j += 16) {
        uint2 q = csrE[j];
        float wv = asf(q.y);
        float2 s = SS[q.x];
        sC = fmaf(wv, s.x, sC);
        sD = fmaf(wv, s.y, sD);
    }
#pragma unroll
    for (int off = 8; off > 0; off >>= 1) {
        sC += __shfl_down(sC, off, 16);
        sD += __shfl_down(sD, off, 16);
    }
    sC = __shfl(sC, 0, 16);
    sD = __shfl(sD, 0, 16);

    uint2 nr = nrec[n];
    float dn = asf(nr.x), id = dn * dn;
    float2 s = SS[n];
    float ssw = sC + id * s.x;
    float ss1 = sD + id * s.y;
    float a0 = asf(nr.y);
    float a1 = -s.x, b1 = -s.y;
    float a2 = 2.f * ssw - a0, b2 = 2.f * ss1 - 1.f;

    const float2* uv2 = (const float2*)suv;
    uint r[4];
#pragma unroll
    for (int q = 0; q < 4; ++q) {
        int p = 4 * l + q;   // float2 index: dims 8l+2q, 8l+2q+1
        float2 u0 = uv2[p],       v0 = uv2[64 + p];
        float2 u1 = uv2[128 + p], v1 = uv2[192 + p];
        float2 u2 = uv2[256 + p], v2 = uv2[320 + p];
        float2 bb = ((const float2*)sbias)[p];
        float o0 = bb.x + a0 * u0.x + v0.x + a1 * u1.x + b1 * v1.x + a2 * u2.x + b2 * v2.x;
        float o1 = bb.y + a0 * u0.y + v0.y + a1 * u1.y + b1 * v1.y + a2 * u2.y + b2 * v2.y;
        r[q] = (uint)f2b(fmaxf(o0, 0.f)) | ((uint)f2b(fmaxf(o1, 0.f)) << 16);
    }
    uint4 w4; w4.x = r[0]; w4.y = r[1]; w4.z = r[2]; w4.w = r[3];
    ((uint4*)(Pb + (size_t)n * DIM))[l] = w4;   // 16 lanes x 16 B = 256 B row
}

// One node per wave64: edge stream wave-uniform (s_load dwordx2), row load
// one coalesced 4B/lane (= full 256B bf16 row), zero shuffles, unroll 8.
// Qb[n] = bf16( -( sum w_e*Xb[src] + Xb[n]/deg ) )
__global__ __launch_bounds__(256) void k_gather1(
        const ushort* __restrict__ Xb, const int* __restrict__ offs,
        const uint2* __restrict__ csrE, const uint2* __restrict__ nrec,
        ushort* __restrict__ Qb) {
    int n = __builtin_amdgcn_readfirstlane(blockIdx.x * 4 + (threadIdx.x >> 6));
    int lane = threadIdx.x & 63;
    int j0 = offs[n], j1 = offs[n + 1];
    const uint* Xu = (const uint*)Xb;   // row = 64 uints
    uint un = Xu[(size_t)n * 64 + lane];
    float dn = asf(nrec[n].x);
    float a0 = 0.f, a1 = 0.f;
#pragma unroll 8
    for (int j = j0; j < j1; ++j) {
        uint2 e = csrE[j];               // wave-uniform -> s_load_dwordx2
        float wv = asf(e.y);
        uint u = Xu[(size_t)e.x * 64 + lane];
        a0 = fmaf(wv, blo(u), a0);
        a1 = fmaf(wv, bhi(u), a1);
    }
    float id = dn * dn;
    uint ow = (uint)f2b(-(a0 + blo(un) * id))
            | ((uint)f2b(-(a1 + bhi(un) * id)) << 16);
    ((uint*)Qb)[(size_t)n * 64 + lane] = ow;
}

// Rb[n] = bf16( -2*( sum w_e*X1b[src] + X1b[n]/deg ) - X0b[n] )
__global__ __launch_bounds__(256) void k_gather2(
        const ushort* __restrict__ X1b, const ushort* __restrict__ X0b,
        const int* __restrict__ offs, const uint2* __restrict__ csrE,
        const uint2* __restrict__ nrec, ushort* __restrict__ Rb) {
    int n = __builtin_amdgcn_readfirstlane(blockIdx.x * 4 + (threadIdx.x >> 6));
    int lane = threadIdx.x & 63;
    int j0 = offs[n], j1 = offs[n + 1];
    const uint* Xu = (const uint*)X1b;
    uint u1n = Xu[(size_t)n * 64 + lane];
    uint u0n = ((const uint*)X0b)[(size_t)n * 64 + lane];
    float dn = asf(nrec[n].x);
    float a0 = 0.f, a1 = 0.f;
#pragma unroll 8
    for (int j = j0; j < j1; ++j) {
        uint2 e = csrE[j];               // wave-uniform -> s_load_dwordx2
        float wv = asf(e.y);
        uint u = Xu[(size_t)e.x * 64 + lane];
        a0 = fmaf(wv, blo(u), a0);
        a1 = fmaf(wv, bhi(u), a1);
    }
    float id = dn * dn;
    uint ow = (uint)f2b(-2.f * (a0 + blo(u1n) * id) - blo(u0n))
            | ((uint)f2b(-2.f * (a1 + bhi(u1n) * id) - bhi(u0n)) << 16);
    ((uint*)Rb)[(size_t)n * 64 + lane] = ow;
}

// MFMA GEMM: outb = bf16(relu([X0|X1|X2] @ W + bias)). 128x128 per block,
// 4 waves each 64x64 quadrant as 4x4 16x16x32 bf16 MFMA tiles.
// Aliasing (outb == X0b) safe: block reads only its own 128 rows, writes last.
__global__ __launch_bounds__(256) void k_gemm(
        const ushort* __restrict__ X0b, const ushort* __restrict__ X1b,
        const ushort* __restrict__ X2b, const ushort* __restrict__ Wt,
        const float* __restrict__ bias, ushort* __restrict__ outb) {
    __shared__ ushort As[128 * PADK];
    __shared__ ushort Bs[128 * PADK];
    int tid = threadIdx.x;
    int nbase = blockIdx.x * 128;
    int wave = tid >> 6, lane = tid & 63;
    int wr = wave >> 1, wc = wave & 1;
    int l15 = lane & 15, quad = lane >> 4;

    float4v acc[4][4];
#pragma unroll
    for (int i = 0; i < 4; ++i)
#pragma unroll
        for (int j = 0; j < 4; ++j) acc[i][j] = (float4v)0.f;

    int srow = tid >> 1, shalf = tid & 1;
    int gm = nbase + srow; if (gm >= NN) gm = NN - 1;

    for (int c = 0; c < 12; ++c) {
        int part = c >> 2;
        int k0 = (c & 3) * 32;
        const ushort* Xp = (part == 0) ? X0b : ((part == 1) ? X1b : X2b);
        const uint4* ga = (const uint4*)(Xp + (size_t)gm * DIM + k0 + shalf * 16);
        uint4 a0 = ga[0], a1 = ga[1];
        const uint4* gb = (const uint4*)(Wt + (size_t)srow * KD + c * 32 + shalf * 16);
        uint4 b0 = gb[0], b1 = gb[1];
        __syncthreads();
        uint4* pa = (uint4*)(As + srow * PADK + shalf * 16);
        pa[0] = a0; pa[1] = a1;
        uint4* pb = (uint4*)(Bs + srow * PADK + shalf * 16);
        pb[0] = b0; pb[1] = b1;
        __syncthreads();
        short8 af[4], bf[4];
#pragma unroll
        for (int i = 0; i < 4; ++i) {
            af[i] = *(const short8*)(As + (wr * 64 + i * 16 + l15) * PADK + quad * 8);
            bf[i] = *(const short8*)(Bs + (wc * 64 + i * 16 + l15) * PADK + quad * 8);
        }
#pragma unroll
        for (int i = 0; i < 4; ++i)
#pragma unroll
            for (int j = 0; j < 4; ++j)
                acc[i][j] = __builtin_amdgcn_mfma_f32_16x16x32_bf16(
                    af[i], bf[j], acc[i][j], 0, 0, 0);
    }

    float bv[4];
#pragma unroll
    for (int j = 0; j < 4; ++j) bv[j] = bias[wc * 64 + j * 16 + l15];
#pragma unroll
    for (int i = 0; i < 4; ++i) {
#pragma unroll
        for (int r = 0; r < 4; ++r) {
            int node = nbase + wr * 64 + i * 16 + quad * 4 + r;
            if (node < NN) {
#pragma unroll
                for (int j = 0; j < 4; ++j) {
                    int col = wc * 64 + j * 16 + l15;
                    outb[(size_t)node * DIM + col] =
                        f2b(fmaxf(acc[i][j][r] + bv[j], 0.f));
                }
            }
        }
    }
}

// Last-layer GEMM with fused prediction head.
__global__ __launch_bounds__(256) void k_gemm_pred(
        const ushort* __restrict__ X0b, const ushort* __restrict__ X1b,
        const ushort* __restrict__ X2b, const ushort* __restrict__ Wt,
        const float* __restrict__ bias, const float* __restrict__ pw,
        const float* __restrict__ pb, float* __restrict__ logits) {
    __shared__ ushort As[128 * PADK];
    __shared__ ushort Bs[128 * PADK];
    __shared__ float lsum[128];
    int tid = threadIdx.x;
    int nbase = blockIdx.x * 128;
    int wave = tid >> 6, lane = tid & 63;
    int wr = wave >> 1, wc = wave & 1;
    int l15 = lane & 15, quad = lane >> 4;

    float4v acc[4][4];
#pragma unroll
    for (int i = 0; i < 4; ++i)
#pragma unroll
        for (int j = 0; j < 4; ++j) acc[i][j] = (float4v)0.f;

    int srow = tid >> 1, shalf = tid & 1;
    int gm = nbase + srow; if (gm >= NN) gm = NN - 1;

    for (int c = 0; c < 12; ++c) {
        int part = c >> 2;
        int k0 = (c & 3) * 32;
        const ushort* Xp = (part == 0) ? X0b : ((part == 1) ? X1b : X2b);
        const uint4* ga = (const uint4*)(Xp + (size_t)gm * DIM + k0 + shalf * 16);
        uint4 a0 = ga[0], a1 = ga[1];
        const uint4* gb = (const uint4*)(Wt + (size_t)srow * KD + c * 32 + shalf * 16);
        uint4 b0 = gb[0], b1 = gb[1];
        __syncthreads();
        uint4* pa = (uint4*)(As + srow * PADK + shalf * 16);
        pa[0] = a0; pa[1] = a1;
        uint4* pb2 = (uint4*)(Bs + srow * PADK + shalf * 16);
        pb2[0] = b0; pb2[1] = b1;
        __syncthreads();
        short8 af[4], bf[4];
#pragma unroll
        for (int i = 0; i < 4; ++i) {
            af[i] = *(const short8*)(As + (wr * 64 + i * 16 + l15) * PADK + quad * 8);
            bf[i] = *(const short8*)(Bs + (wc * 64 + i * 16 + l15) * PADK + quad * 8);
        }
#pragma unroll
        for (int i = 0; i < 4; ++i)
#pragma unroll
            for (int j = 0; j < 4; ++j)
                acc[i][j] = __builtin_amdgcn_mfma_f32_16x16x32_bf16(
                    af[i], bf[j], acc[i][j], 0, 0, 0);
    }

    __syncthreads();
    if (tid < 128) lsum[tid] = 0.f;
    __syncthreads();
    float bv[4], pwv[4];
#pragma unroll
    for (int j = 0; j < 4; ++j) {
        int col = wc * 64 + j * 16 + l15;
        bv[j] = bias[col];
        pwv[j] = pw[col];
    }
#pragma unroll
    for (int i = 0; i < 4; ++i) {
#pragma unroll
        for (int r = 0; r < 4; ++r) {
            float local = 0.f;
#pragma unroll
            for (int j = 0; j < 4; ++j)
                local = fmaf(fmaxf(acc[i][j][r] + bv[j], 0.f), pwv[j], local);
            local += __shfl_xor(local, 1, 64);
            local += __shfl_xor(local, 2, 64);
            local += __shfl_xor(local, 4, 64);
            local += __shfl_xor(local, 8, 64);
            if (l15 == 0)
                atomicAdd(&lsum[wr * 64 + i * 16 + quad * 4 + r], local);
        }
    }
    __syncthreads();
    if (tid < 128) {
        int node = nbase + tid;
        if (node < NN) logits[node] = lsum[tid] + pb[0];
    }
}

extern "C" void kernel_launch(void* const* d_in, const int* in_sizes, int n_in,
                              void* d_out, int out_size, void* d_ws, size_t ws_size,
                              hipStream_t stream) {
    int i_weights = 0, i_src = 1, i_dst = 2, i_lw = 3, i_lb = 4,
        i_cw = 5, i_cb = 6, i_pw = 7, i_pb = 8;
    {
        int seen600k = 0, seen128 = 0;
        for (int i = 0; i < n_in; ++i) {
            int s = in_sizes[i];
            if (s == 50000) i_weights = i;
            else if (s == 600000) { if (seen600k == 0) i_src = i; else i_dst = i; ++seen600k; }
            else if (s == 128) { if (seen128 == 0) i_lw = i; else if (seen128 == 1) i_lb = i; else i_pw = i; ++seen128; }
            else if (s == 147456) i_cw = i;
            else if (s == 384) i_cb = i;
            else if (s == 1) i_pb = i;
        }
    }
    const float* weights = (const float*)d_in[i_weights];
    const int*   src     = (const int*)d_in[i_src];
    const int*   dst     = (const int*)d_in[i_dst];
    const float* lin_w   = (const float*)d_in[i_lw];
    const float* lin_b   = (const float*)d_in[i_lb];
    const float* cheb_w  = (const float*)d_in[i_cw];
    const float* cheb_b  = (const float*)d_in[i_cb];
    const float* pred_w  = (const float*)d_in[i_pw];
    const float* pred_b  = (const float*)d_in[i_pb];
    float* out = (float*)d_out;

    // Workspace (~27 MB), 8B-aligned blocks first:
    uint2*  csrE    = (uint2*)d_ws;                  // 600000 x 8B {src,w}
    uint2*  nrec    = csrE + NE;                     // 50048 x 8B {dinv,w}
    float2* SS      = (float2*)(nrec + 50048);       // 50048 float2 {Sw, S1}
    float*  uv      = (float*)(SS + 50048);          // 768 floats
    int*    offs    = (int*)(uv + 768);              // 50056 ints
    int*    cnt     = offs + 50056;                  // 50176 ints
    int*    incl    = cnt + 50176;                   // 50176 ints
    int*    bsums   = incl + 50176;                  // 256 ints
    int*    rank    = bsums + 256;                   // 600000 ints
    uint*   csrS    = (uint*)(rank + NE);            // 600000 uints
    ushort* Pb      = (ushort*)(csrS + NE);          // 6.4M bf16 (state)
    ushort* Qb      = Pb + (size_t)NN * DIM;         // 6.4M bf16 (X1)
    ushort* Rb      = Qb + (size_t)NN * DIM;         // 6.4M bf16 (X2)
    ushort* Wtb     = Rb + (size_t)NN * DIM;         // 442368 bf16

    // --- CSR build + weight transpose + uv (once per launch) ---
    k_init<<<631, 256, 0, stream>>>(cnt, cheb_w, Wtb, lin_w, lin_b, uv);
    k_hist<<<2344, 256, 0, stream>>>(dst, cnt, rank);
    k_scan1<<<196, 256, 0, stream>>>(cnt, incl, bsums, weights, nrec);
    k_scan3<<<196, 256, 0, stream>>>(cnt, incl, bsums, offs);
    k_fill4<<<2344, 256, 0, stream>>>(src, dst, rank, offs, csrS);
    k_csrfin<<<3125, 256, 0, stream>>>(offs, csrS, nrec, csrE, SS);

    // --- layer 1: fused SpMV #2 + layer-1 output ---
    k_spmv2l1<<<3125, 256, 0, stream>>>(offs, csrE, SS, nrec, uv, cheb_b, Pb);

    // --- layer 2 ---
    k_gather1<<<12500, 256, 0, stream>>>(Pb, offs, csrE, nrec, Qb);
    k_gather2<<<12500, 256, 0, stream>>>(Qb, Pb, offs, csrE, nrec, Rb);
    k_gemm<<<391, 256, 0, stream>>>(Pb, Qb, Rb, Wtb + (size_t)KD * DIM,
                                    cheb_b + DIM, Pb);
    // --- layer 3 (fused prediction head) ---
    k_gather1<<<12500, 256, 0, stream>>>(Pb, offs, csrE, nrec, Qb);
    k_gather2<<<12500, 256, 0, stream>>>(Qb, Pb, offs, csrE, nrec, Rb);
    k_gemm_pred<<<391, 256, 0, stream>>>(Pb, Qb, Rb, Wtb + (size_t)2 * KD * DIM,
                                         cheb_b + 2 * DIM, pred_w, pred_b, out);
}